// Round 1
// baseline (1071.230 us; speedup 1.0000x reference)
//
#include <hip/hip_runtime.h>

// SinkhornOT fused kernel for MI355X (gfx950).
// Pipeline per batch element b (one 512-thread block):
//   X=[slots_q[b];slots_r[b]] (64x256) -> bf16 hi/lo LDS
//   H = relu(X@W1+b1)   (bf16x2-split MFMA, 3 products)
//   Q = H@W2+b2         (fp32 in LDS, overlays X)
//   C = cdist(q,r)      (vector fp32 from swizzled LDS)
//   15 log-domain Sinkhorn iters + T + 3 mesh iters + cost/similarity
// W1/W2 are pre-split into bf16 hi/lo MFMA B-fragments in d_ws by prep_w.

typedef unsigned short u16;
typedef short short8  __attribute__((ext_vector_type(8)));
typedef short short4v __attribute__((ext_vector_type(4)));
typedef float f32x4   __attribute__((ext_vector_type(4)));

#define MFMA(a, b, c) __builtin_amdgcn_mfma_f32_16x16x32_bf16((a), (b), (c), 0, 0, 0)

static __device__ __forceinline__ u16 f2bf(float f) {  // RNE float->bf16 (finite inputs)
  unsigned u = __float_as_uint(f);
  unsigned r = (u + 0x7FFFu + ((u >> 16) & 1u)) >> 16;
  return (u16)r;
}
static __device__ __forceinline__ float bf2f(u16 h) {
  return __uint_as_float(((unsigned)h) << 16);
}
// [64][256] LDS tiles: 4-element granule XOR-swizzled by row (kills 16-way conflicts, G4)
static __device__ __forceinline__ int swzi(int r, int c) {
  return r * 256 + ((((c >> 2) ^ (r & 7)) << 2) | (c & 3));
}
static __device__ __forceinline__ int swzg(int r, int g) {  // granule g = c>>2, 8B/16B unit
  return r * 256 + ((g ^ (r & 7)) << 2);
}

// ---------------- W fragment prep ----------------
// MFMA 16x16x32 A/B k-slot map (used consistently on BOTH sides, so any bijection works):
//   lane l, elem j: k_local = 4*(l>>4) + (j&3) + 16*(j>>2);  A row / B col = l&15.
// ws layout (u16 units): [mat][hi|lo][ (ki*16+ctg)*64+lane ][8]
//   mat*131072 + sel*65536 + frag*8 + j,  frag = (ki*16 + ctg)*64 + lane
__global__ __launch_bounds__(256) void prep_w(const float* __restrict__ W1,
                                              const float* __restrict__ W2,
                                              u16* __restrict__ ws) {
  int id = blockIdx.x * 256 + threadIdx.x;  // 0..131071
  int mat = id >> 16;
  int e = id & 65535;        // e = k*256 + n  (W is [k][n] row-major)
  int k = e >> 8, n = e & 255;
  float wv = (mat ? W2 : W1)[e];
  u16 h = f2bf(wv);
  u16 l = f2bf(wv - bf2f(h));
  int ki = k >> 5, kl = k & 31;
  int g = (kl >> 2) & 3;
  int j = (kl & 3) | ((kl >> 4) << 2);
  int lane = g * 16 + (n & 15);
  int ctg = n >> 4;
  int idx = mat * 131072 + ((((ki * 16 + ctg) * 64 + lane) << 3) | j);
  ws[idx] = h;
  ws[idx + 65536] = l;
}

// ---------------- fused main kernel ----------------
struct __align__(16) SMem {
  union {
    struct { u16 Xhi[64 * 256]; u16 Xlo[64 * 256]; } x;  // GEMM1 A (bf16 hi/lo)
    float Qf[64 * 256];                                  // GEMM2 output (fp32), overlays X
  } xq;
  u16 Hhi[64 * 256];   // GEMM2 A
  u16 Hlo[64 * 256];
  float Cm[32 * 33];   // +1 pad
  float Tm[32 * 33];
  float la[32];
  float lb[32];
  float part[32];
};

// One 64x256 * 256x256 GEMM with bf16x2 split (acc += Ahi*Bhi + Alo*Bhi + Ahi*Blo).
// wave w owns output cols [32w,32w+32): acc[rt][ct] is 16x16 tile (rt: rows, ct: cols).
static __device__ __forceinline__ void gemm_tiles(const u16* __restrict__ Ahi,
                                                  const u16* __restrict__ Alo,
                                                  const u16* __restrict__ wf,
                                                  int w, int lane, f32x4 acc[4][2]) {
  const int g = lane >> 4, ln = lane & 15;
#pragma unroll
  for (int rt = 0; rt < 4; ++rt)
#pragma unroll
    for (int ct = 0; ct < 2; ++ct) acc[rt][ct] = f32x4{0.f, 0.f, 0.f, 0.f};

  for (int ki = 0; ki < 8; ++ki) {
    short8 bh[2], bl[2];
#pragma unroll
    for (int ct = 0; ct < 2; ++ct) {
      const u16* p = wf + (((ki * 16 + (2 * w + ct)) * 64 + lane) << 3);
      bh[ct] = *reinterpret_cast<const short8*>(p);            // coalesced dwordx4
      bl[ct] = *reinterpret_cast<const short8*>(p + 65536);
    }
    short8 ah[4], al[4];
#pragma unroll
    for (int rt = 0; rt < 4; ++rt) {
      int row = rt * 16 + ln;
      int kg = ki * 8 + g;  // elem j0..3 at granule kg, j4..7 at kg+4
      short4v h0 = *reinterpret_cast<const short4v*>(&Ahi[swzg(row, kg)]);
      short4v h1 = *reinterpret_cast<const short4v*>(&Ahi[swzg(row, kg + 4)]);
      short4v l0 = *reinterpret_cast<const short4v*>(&Alo[swzg(row, kg)]);
      short4v l1 = *reinterpret_cast<const short4v*>(&Alo[swzg(row, kg + 4)]);
      ah[rt] = __builtin_shufflevector(h0, h1, 0, 1, 2, 3, 4, 5, 6, 7);
      al[rt] = __builtin_shufflevector(l0, l1, 0, 1, 2, 3, 4, 5, 6, 7);
    }
#pragma unroll
    for (int rt = 0; rt < 4; ++rt)
#pragma unroll
      for (int ct = 0; ct < 2; ++ct) {
        acc[rt][ct] = MFMA(ah[rt], bh[ct], acc[rt][ct]);
        acc[rt][ct] = MFMA(al[rt], bh[ct], acc[rt][ct]);
        acc[rt][ct] = MFMA(ah[rt], bl[ct], acc[rt][ct]);
      }
  }
}

__global__ __launch_bounds__(512, 2) void sink_main(
    const float* __restrict__ slots_q, const float* __restrict__ slots_r,
    const float* __restrict__ b1, const float* __restrict__ b2,
    const u16* __restrict__ wfrag,
    float* __restrict__ simO, float* __restrict__ TO,
    float* __restrict__ CO, float* __restrict__ costO) {
  __shared__ SMem sm;
  const int tid = threadIdx.x;
  const int b = blockIdx.x;
  const int w = tid >> 6, lane = tid & 63;
  const int g = lane >> 4, ln = lane & 15;

  // ---- stage X = [q;r] as bf16 hi/lo, swizzled ----
  {
    const float* srcq = slots_q + (size_t)b * 8192;
    const float* srcr = slots_r + (size_t)b * 8192;
#pragma unroll
    for (int ii = 0; ii < 8; ++ii) {
      int i = tid + ii * 512;     // granule index: row = i>>6 (wave-uniform), c4 = lane
      int r = i >> 6;
      int c4 = i & 63;
      const float* src = (r < 32) ? (srcq + r * 256) : (srcr + (r - 32) * 256);
      float4 v = *reinterpret_cast<const float4*>(src + (c4 << 2));
      u16 h0 = f2bf(v.x), h1 = f2bf(v.y), h2 = f2bf(v.z), h3 = f2bf(v.w);
      u16 l0 = f2bf(v.x - bf2f(h0)), l1 = f2bf(v.y - bf2f(h1));
      u16 l2 = f2bf(v.z - bf2f(h2)), l3 = f2bf(v.w - bf2f(h3));
      int o = swzg(r, c4);
      uint2 hp, lp;
      hp.x = (unsigned)h0 | ((unsigned)h1 << 16);
      hp.y = (unsigned)h2 | ((unsigned)h3 << 16);
      lp.x = (unsigned)l0 | ((unsigned)l1 << 16);
      lp.y = (unsigned)l2 | ((unsigned)l3 << 16);
      *reinterpret_cast<uint2*>(&sm.xq.x.Xhi[o]) = hp;
      *reinterpret_cast<uint2*>(&sm.xq.x.Xlo[o]) = lp;
    }
  }
  __syncthreads();

  f32x4 acc[4][2];
  // ---- GEMM1: H = relu(X@W1 + b1) ----
  gemm_tiles(sm.xq.x.Xhi, sm.xq.x.Xlo, wfrag, w, lane, acc);
#pragma unroll
  for (int ct = 0; ct < 2; ++ct) {
    int col = 32 * w + ct * 16 + ln;
    float bv = b1[col];
#pragma unroll
    for (int rt = 0; rt < 4; ++rt)
#pragma unroll
      for (int r = 0; r < 4; ++r) {
        int row = rt * 16 + 4 * g + r;   // D layout: row = 4*(lane>>4)+reg, col = lane&15
        float v = fmaxf(acc[rt][ct][r] + bv, 0.0f);
        u16 h = f2bf(v);
        sm.Hhi[swzi(row, col)] = h;
        sm.Hlo[swzi(row, col)] = f2bf(v - bf2f(h));
      }
  }
  __syncthreads();

  // ---- GEMM2: Q = H@W2 + b2 (fp32, overlays dead X region) ----
  gemm_tiles(sm.Hhi, sm.Hlo, wfrag + 131072, w, lane, acc);
#pragma unroll
  for (int ct = 0; ct < 2; ++ct) {
    int col = 32 * w + ct * 16 + ln;
    float bv = b2[col];
#pragma unroll
    for (int rt = 0; rt < 4; ++rt)
#pragma unroll
      for (int r = 0; r < 4; ++r) {
        int row = rt * 16 + 4 * g + r;
        sm.xq.Qf[swzi(row, col)] = acc[rt][ct][r] + bv;
      }
  }
  if (tid < 32) sm.lb[tid] = 0.0f;
  __syncthreads();

  // ---- cdist: C[k][m] = ||q_k - r_m|| ----
  {
    int k = tid >> 4;   // 0..31
    int mg = tid & 15;  // m = mg and mg+16
    float s0 = 0.f, s1 = 0.f;
    for (int c4 = 0; c4 < 64; ++c4) {
      float4 qv = *reinterpret_cast<const float4*>(&sm.xq.Qf[swzg(k, c4)]);
      float4 r0 = *reinterpret_cast<const float4*>(&sm.xq.Qf[swzg(32 + mg, c4)]);
      float4 r1 = *reinterpret_cast<const float4*>(&sm.xq.Qf[swzg(48 + mg, c4)]);
      float d;
      d = qv.x - r0.x; s0 += d * d;  d = qv.y - r0.y; s0 += d * d;
      d = qv.z - r0.z; s0 += d * d;  d = qv.w - r0.w; s0 += d * d;
      d = qv.x - r1.x; s1 += d * d;  d = qv.y - r1.y; s1 += d * d;
      d = qv.z - r1.z; s1 += d * d;  d = qv.w - r1.w; s1 += d * d;
    }
    sm.Cm[k * 33 + mg]      = sqrtf(s0);
    sm.Cm[k * 33 + mg + 16] = sqrtf(s1);
  }
  __syncthreads();

  // ---- Sinkhorn (log domain). wave w owns rows/cols 4w..4w+3; 16-lane shfl LSE. ----
  const int rk = 4 * w + g;
  const float c0  = sm.Cm[rk * 33 + ln];
  const float c1  = sm.Cm[rk * 33 + ln + 16];
  const float cc0 = sm.Cm[ln * 33 + rk];
  const float cc1 = sm.Cm[(ln + 16) * 33 + rk];
  const float lkr0 = -20.0f * c0, lkr1 = -20.0f * c1;   // log_K = -C/0.05
  const float lkc0 = -20.0f * cc0, lkc1 = -20.0f * cc1;

  for (int it = 0; it < 15; ++it) {
    // log_a[k] = -LSE_m(log_K[k][m] + log_b[m])
    float v0 = lkr0 + sm.lb[ln];
    float v1 = lkr1 + sm.lb[ln + 16];
    float mx = fmaxf(v0, v1);
    mx = fmaxf(mx, __shfl_xor(mx, 1)); mx = fmaxf(mx, __shfl_xor(mx, 2));
    mx = fmaxf(mx, __shfl_xor(mx, 4)); mx = fmaxf(mx, __shfl_xor(mx, 8));
    float s = __expf(v0 - mx) + __expf(v1 - mx);
    s += __shfl_xor(s, 1); s += __shfl_xor(s, 2);
    s += __shfl_xor(s, 4); s += __shfl_xor(s, 8);
    if (ln == 0) sm.la[rk] = -(mx + __logf(s));
    __syncthreads();
    // log_b[m] = -LSE_k(log_K[k][m] + log_a[k])
    float u0 = lkc0 + sm.la[ln];
    float u1 = lkc1 + sm.la[ln + 16];
    mx = fmaxf(u0, u1);
    mx = fmaxf(mx, __shfl_xor(mx, 1)); mx = fmaxf(mx, __shfl_xor(mx, 2));
    mx = fmaxf(mx, __shfl_xor(mx, 4)); mx = fmaxf(mx, __shfl_xor(mx, 8));
    s = __expf(u0 - mx) + __expf(u1 - mx);
    s += __shfl_xor(s, 1); s += __shfl_xor(s, 2);
    s += __shfl_xor(s, 4); s += __shfl_xor(s, 8);
    if (ln == 0) sm.lb[rk] = -(mx + __logf(s));
    __syncthreads();
  }

  // T = exp(log_K + la + lb)
  {
    float laf = sm.la[rk];
    sm.Tm[rk * 33 + ln]      = __expf(lkr0 + laf + sm.lb[ln]);
    sm.Tm[rk * 33 + ln + 16] = __expf(lkr1 + laf + sm.lb[ln + 16]);
  }
  __syncthreads();

  // ---- mesh iterations: T=T^2; row-normalize; col-normalize ----
  for (int mi = 0; mi < 3; ++mi) {
    float a0 = sm.Tm[rk * 33 + ln];      a0 *= a0;
    float a1 = sm.Tm[rk * 33 + ln + 16]; a1 *= a1;
    float s = a0 + a1;
    s += __shfl_xor(s, 1); s += __shfl_xor(s, 2);
    s += __shfl_xor(s, 4); s += __shfl_xor(s, 8);
    float inv = 1.0f / (s + 1e-8f);
    sm.Tm[rk * 33 + ln]      = a0 * inv;
    sm.Tm[rk * 33 + ln + 16] = a1 * inv;
    __syncthreads();
    float u0 = sm.Tm[ln * 33 + rk];
    float u1 = sm.Tm[(ln + 16) * 33 + rk];
    s = u0 + u1;
    s += __shfl_xor(s, 1); s += __shfl_xor(s, 2);
    s += __shfl_xor(s, 4); s += __shfl_xor(s, 8);
    inv = 1.0f / (s + 1e-8f);
    sm.Tm[ln * 33 + rk]        = u0 * inv;
    sm.Tm[(ln + 16) * 33 + rk] = u1 * inv;
    __syncthreads();
  }

  // ---- cost = sum(T*C); outputs ----
  {
    float p = sm.Tm[rk * 33 + ln] * c0 + sm.Tm[rk * 33 + ln + 16] * c1;
    p += __shfl_xor(p, 1); p += __shfl_xor(p, 2);
    p += __shfl_xor(p, 4); p += __shfl_xor(p, 8);
    if (ln == 0) sm.part[rk] = p;
  }
  __syncthreads();

  {
    float2* TOp = reinterpret_cast<float2*>(TO + (size_t)b * 1024);
    float2* COp = reinterpret_cast<float2*>(CO + (size_t)b * 1024);
    int idx = tid * 2;
    int kk = idx >> 5, mm = idx & 31;
    float2 tv, cv;
    tv.x = sm.Tm[kk * 33 + mm]; tv.y = sm.Tm[kk * 33 + mm + 1];
    cv.x = sm.Cm[kk * 33 + mm]; cv.y = sm.Cm[kk * 33 + mm + 1];
    TOp[tid] = tv;
    COp[tid] = cv;
  }
  if (tid < 64) {
    float v2 = (lane < 32) ? sm.part[lane] : 0.0f;
    v2 += __shfl_xor(v2, 1);  v2 += __shfl_xor(v2, 2);  v2 += __shfl_xor(v2, 4);
    v2 += __shfl_xor(v2, 8);  v2 += __shfl_xor(v2, 16); v2 += __shfl_xor(v2, 32);
    if (lane == 0) {
      costO[b] = v2;
      simO[b] = 1.0f / (1.0f + __expf(v2));  // == sigmoid(-cost)
    }
  }
}

extern "C" void kernel_launch(void* const* d_in, const int* in_sizes, int n_in,
                              void* d_out, int out_size, void* d_ws, size_t ws_size,
                              hipStream_t stream) {
  const float* slots_q = (const float*)d_in[0];
  const float* slots_r = (const float*)d_in[1];
  const float* W1 = (const float*)d_in[2];
  const float* b1 = (const float*)d_in[3];
  const float* W2 = (const float*)d_in[4];
  const float* b2 = (const float*)d_in[5];
  float* out = (float*)d_out;

  const int Bn = in_sizes[0] / 8192;  // 32*256 elems per batch element
  u16* ws = (u16*)d_ws;               // 512 KB: W1/W2 bf16 hi/lo fragments

  prep_w<<<dim3(512), dim3(256), 0, stream>>>(W1, W2, ws);

  float* simO = out;
  float* TO = out + Bn;
  float* CO = TO + (size_t)Bn * 1024;
  float* costO = CO + (size_t)Bn * 1024;
  sink_main<<<dim3(Bn), dim3(512), 0, stream>>>(slots_q, slots_r, b1, b2, ws,
                                                simO, TO, CO, costO);
}

// Round 2
// 382.478 us; speedup vs baseline: 2.8008x; 2.8008x over previous
//
#include <hip/hip_runtime.h>

// SinkhornOT, split-kernel version for MI355X (gfx950).
// Kernel A (gemm_cdist, 1 block = 1 batch elem, 512 thr, 64KB LDS, 3 barriers):
//   X=[q;r] (64x256) -> bf16 fragment-major LDS -> H=relu(X@W1+b1) (MFMA)
//   -> Q=H@W2+b2 (bf16, swizzled, overlays X) -> C=cdist -> global CO.
// Kernel B (sinkhorn_mesh, 1 wave = 1 problem, no barriers, wave-sync LDS):
//   15 log-domain Sinkhorn iters + T + 3 mesh iters + cost/sim + T out.
// prep_w packs W1/W2 as bf16 MFMA B-fragments (k-map k_local = 8g+j, used
// consistently for A and B so the bijection cancels).

typedef unsigned short u16;
typedef short short8 __attribute__((ext_vector_type(8)));
typedef float f32x4  __attribute__((ext_vector_type(4)));

#define MFMA(a, b, c) __builtin_amdgcn_mfma_f32_16x16x32_bf16((a), (b), (c), 0, 0, 0)

static __device__ __forceinline__ u16 f2bf(float f) {  // RNE float->bf16 (finite)
  unsigned u = __float_as_uint(f);
  return (u16)((u + 0x7FFFu + ((u >> 16) & 1u)) >> 16);
}
static __device__ __forceinline__ float bf2f(u16 h) {
  return __uint_as_float(((unsigned)h) << 16);
}

// ---------------- W fragment prep (hi-only bf16) ----------------
// k-slot map: lane l = g*16 + (n&15) holds B[k = ki*32 + 8g + j][col = 16*ctg + (n&15)]
// ws u16 layout: mat*65536 + ((ki*16 + ctg)*64 + lane)*8 + j   (256 KB total)
__global__ __launch_bounds__(256) void prep_w(const float* __restrict__ W1,
                                              const float* __restrict__ W2,
                                              u16* __restrict__ ws) {
  int id = blockIdx.x * 256 + threadIdx.x;  // 0..131071
  int mat = id >> 16;
  int e = id & 65535;   // e = k*256 + n
  int k = e >> 8, n = e & 255;
  float wv = (mat ? W2 : W1)[e];
  int ki = k >> 5, kl = k & 31;
  int g = kl >> 3, j = kl & 7;
  int lane = g * 16 + (n & 15);
  int ctg = n >> 4;
  ws[mat * 65536 + ((((ki * 16 + ctg) * 64 + lane) << 3) | j)] = f2bf(wv);
}

// ---------------- kernel A ----------------
struct __align__(16) SMemA {
  union { u16 Xf[16384]; u16 Qbf[16384]; } u;  // 32KB: A-fragments, then Q bf16
  u16 Hf[16384];                               // 32KB: H A-fragments
};

// 64x256 @ 256x256: A fragment-major [ki*4+rt][lane][8] (contiguous b128/lane),
// B fragments from global ws. Wave w owns output cols [32w, 32w+32).
static __device__ __forceinline__ void gemm_frag(const u16* __restrict__ Af,
                                                 const u16* __restrict__ wf,
                                                 int w, int lane, f32x4 acc[4][2]) {
#pragma unroll
  for (int rt = 0; rt < 4; ++rt) {
    acc[rt][0] = f32x4{0.f, 0.f, 0.f, 0.f};
    acc[rt][1] = f32x4{0.f, 0.f, 0.f, 0.f};
  }
#pragma unroll
  for (int ki = 0; ki < 8; ++ki) {
    const u16* bp = wf + (((ki * 16 + 2 * w) * 64 + lane) << 3);
    short8 b0 = *reinterpret_cast<const short8*>(bp);        // 16B/lane, coalesced
    short8 b1 = *reinterpret_cast<const short8*>(bp + 512);  // ct=1 record
    short8 a[4];
#pragma unroll
    for (int rt = 0; rt < 4; ++rt)
      a[rt] = *reinterpret_cast<const short8*>(Af + (((ki * 4 + rt) * 64 + lane) << 3));
#pragma unroll
    for (int rt = 0; rt < 4; ++rt) {
      acc[rt][0] = MFMA(a[rt], b0, acc[rt][0]);
      acc[rt][1] = MFMA(a[rt], b1, acc[rt][1]);
    }
  }
}

__global__ __launch_bounds__(512, 4) void gemm_cdist(
    const float* __restrict__ slots_q, const float* __restrict__ slots_r,
    const float* __restrict__ b1, const float* __restrict__ b2,
    const u16* __restrict__ ws, float* __restrict__ CO) {
  __shared__ SMemA sm;
  const int tid = threadIdx.x, b = blockIdx.x;
  const int w = tid >> 6, lane = tid & 63, g = lane >> 4, ln = lane & 15;

  // ---- stage X fragment-major: slot s = (ki*4+rt)*64 + g*16 + ln ----
  {
    const float* srcq = slots_q + (size_t)b * 8192;
    const float* srcr = slots_r + (size_t)b * 8192;
#pragma unroll
    for (int ii = 0; ii < 4; ++ii) {
      int s = tid + ii * 512;  // 0..2047
      int ki = s >> 8, rt = (s >> 6) & 3, sg = (s >> 4) & 3, sln = s & 15;
      int row = rt * 16 + sln;
      const float* src = (row < 32) ? (srcq + row * 256) : (srcr + (row - 32) * 256);
      int k0 = ki * 32 + sg * 8;
      float4 v0 = *reinterpret_cast<const float4*>(src + k0);
      float4 v1 = *reinterpret_cast<const float4*>(src + k0 + 4);
      short8 o;
      o[0] = (short)f2bf(v0.x); o[1] = (short)f2bf(v0.y);
      o[2] = (short)f2bf(v0.z); o[3] = (short)f2bf(v0.w);
      o[4] = (short)f2bf(v1.x); o[5] = (short)f2bf(v1.y);
      o[6] = (short)f2bf(v1.z); o[7] = (short)f2bf(v1.w);
      *reinterpret_cast<short8*>(&sm.u.Xf[s << 3]) = o;  // contiguous, conflict-free
    }
  }
  float bv1a = b1[32 * w + ln], bv1b = b1[32 * w + 16 + ln];
  float bv2a = b2[32 * w + ln], bv2b = b2[32 * w + 16 + ln];
  __syncthreads();

  f32x4 acc[4][2];
  // ---- GEMM1: H = relu(X@W1 + b1), write H as fragments (rec ki2 = w) ----
  gemm_frag(sm.u.Xf, ws, w, lane, acc);
#pragma unroll
  for (int ct = 0; ct < 2; ++ct) {
    float bv = ct ? bv1b : bv1a;
#pragma unroll
    for (int rt = 0; rt < 4; ++rt)
#pragma unroll
      for (int ri = 0; ri < 4; ++ri) {
        // D layout: row = rt*16 + 4g + ri, col = 32w + 16ct + ln (verified r1)
        int lane2 = (2 * ct + (ln >> 3)) * 16 + 4 * g + ri;
        sm.Hf[(((w * 4 + rt) * 64 + lane2) << 3) | (ln & 7)] =
            f2bf(fmaxf(acc[rt][ct][ri] + bv, 0.0f));
      }
  }
  __syncthreads();

  // ---- GEMM2: Q = H@W2 + b2 -> bf16 [64][256], 16B-unit XOR swizzle ----
  gemm_frag(sm.Hf, ws + 65536, w, lane, acc);
#pragma unroll
  for (int ct = 0; ct < 2; ++ct) {
    float bv = ct ? bv2b : bv2a;
    int col = 32 * w + 16 * ct + ln;
#pragma unroll
    for (int rt = 0; rt < 4; ++rt)
#pragma unroll
      for (int ri = 0; ri < 4; ++ri) {
        int row = rt * 16 + 4 * g + ri;
        int unit = (col >> 3) ^ (row & 15);
        sm.u.Qbf[row * 256 + (unit << 3) + (col & 7)] = f2bf(acc[rt][ct][ri] + bv);
      }
  }
  __syncthreads();

  // ---- cdist -> CO[b][32][32] (fp32 accum from bf16 q/r) ----
  {
    int k = tid >> 4, mg = tid & 15;  // thread does C[k][mg], C[k][mg+16]
    int kx = k & 15;                  // (32+mg)&15 == (48+mg)&15 == mg
    float s0 = 0.f, s1 = 0.f;
    const u16* Q = sm.u.Qbf;
#pragma unroll 4
    for (int cb = 0; cb < 32; ++cb) {
      short8 qv = *reinterpret_cast<const short8*>(Q + k * 256 + ((cb ^ kx) << 3));
      short8 r0 = *reinterpret_cast<const short8*>(Q + (32 + mg) * 256 + ((cb ^ mg) << 3));
      short8 r1 = *reinterpret_cast<const short8*>(Q + (48 + mg) * 256 + ((cb ^ mg) << 3));
#pragma unroll
      for (int i = 0; i < 8; ++i) {
        float qf = bf2f((u16)qv[i]);
        float d0 = qf - bf2f((u16)r0[i]);
        float d1 = qf - bf2f((u16)r1[i]);
        s0 = fmaf(d0, d0, s0);
        s1 = fmaf(d1, d1, s1);
      }
    }
    float* Cp = CO + (size_t)b * 1024 + k * 32;
    Cp[mg] = sqrtf(s0);
    Cp[mg + 16] = sqrtf(s1);
  }
}

// ---------------- kernel B: 1 wave = 1 problem, no barriers ----------------
__global__ __launch_bounds__(256, 4) void sinkhorn_mesh(
    const float* __restrict__ CO, float* __restrict__ simO,
    float* __restrict__ TO, float* __restrict__ costO, int Bn) {
  __shared__ float Wl[4][32 * 33];
  __shared__ float ABl[4][64];
  const int wv = threadIdx.x >> 6, lane = threadIdx.x & 63;
  const int p = blockIdx.x * 4 + wv;
  if (p >= Bn) return;
  const int h = lane >> 5, q = lane & 31;  // q = row k (row ops) / col (col ops)
  float* Wm = Wl[wv];
  float* LA = ABl[wv];
  float* LB = ABl[wv] + 32;
  const float* Cp = CO + (size_t)p * 1024;

  // lane holds row q cols [16h,16h+16) in lkr, col q rows [16h,16h+16) in lkc
  float lkr[16], lkc[16];
#pragma unroll
  for (int jj = 0; jj < 4; ++jj) {
    float4 v = *reinterpret_cast<const float4*>(Cp + q * 32 + h * 16 + jj * 4);
    int base = q * 33 + h * 16 + jj * 4;
    Wm[base + 0] = v.x; Wm[base + 1] = v.y; Wm[base + 2] = v.z; Wm[base + 3] = v.w;
    lkr[jj * 4 + 0] = -20.f * v.x; lkr[jj * 4 + 1] = -20.f * v.y;
    lkr[jj * 4 + 2] = -20.f * v.z; lkr[jj * 4 + 3] = -20.f * v.w;
  }
  LB[q] = 0.0f;
  __builtin_amdgcn_wave_barrier();
#pragma unroll
  for (int j = 0; j < 16; ++j) lkc[j] = -20.f * Wm[(h * 16 + j) * 33 + q];

  for (int it = 0; it < 15; ++it) {
    float v[16], mx, s;
#pragma unroll
    for (int j = 0; j < 16; ++j) v[j] = lkr[j] + LB[h * 16 + j];
    mx = v[0];
#pragma unroll
    for (int j = 1; j < 16; ++j) mx = fmaxf(mx, v[j]);
    mx = fmaxf(mx, __shfl_xor(mx, 32));
    s = 0.f;
#pragma unroll
    for (int j = 0; j < 16; ++j) s += __expf(v[j] - mx);
    s += __shfl_xor(s, 32);
    LA[q] = -(mx + __logf(s));  // both halves write identical value
    __builtin_amdgcn_wave_barrier();
#pragma unroll
    for (int j = 0; j < 16; ++j) v[j] = lkc[j] + LA[h * 16 + j];
    mx = v[0];
#pragma unroll
    for (int j = 1; j < 16; ++j) mx = fmaxf(mx, v[j]);
    mx = fmaxf(mx, __shfl_xor(mx, 32));
    s = 0.f;
#pragma unroll
    for (int j = 0; j < 16; ++j) s += __expf(v[j] - mx);
    s += __shfl_xor(s, 32);
    LB[q] = -(mx + __logf(s));
    __builtin_amdgcn_wave_barrier();
  }

  // T = exp(log_K + la + lb), row view
  float t[16];
  {
    float la = LA[q];
#pragma unroll
    for (int j = 0; j < 16; ++j) t[j] = __expf(lkr[j] + la + LB[h * 16 + j]);
  }

  // mesh: T=T^2; row-norm; col-norm (via LDS transpose; wave-sync only)
  for (int mi = 0; mi < 3; ++mi) {
    float s = 0.f;
#pragma unroll
    for (int j = 0; j < 16; ++j) { t[j] *= t[j]; s += t[j]; }
    s += __shfl_xor(s, 32);
    float inv = 1.0f / (s + 1e-8f);
#pragma unroll
    for (int j = 0; j < 16; ++j) Wm[q * 33 + h * 16 + j] = t[j] * inv;
    __builtin_amdgcn_wave_barrier();
#pragma unroll
    for (int j = 0; j < 16; ++j) t[j] = Wm[(h * 16 + j) * 33 + q];  // col view
    s = 0.f;
#pragma unroll
    for (int j = 0; j < 16; ++j) s += t[j];
    s += __shfl_xor(s, 32);
    inv = 1.0f / (s + 1e-8f);
#pragma unroll
    for (int j = 0; j < 16; ++j) Wm[(h * 16 + j) * 33 + q] = t[j] * inv;
    __builtin_amdgcn_wave_barrier();
#pragma unroll
    for (int j = 0; j < 16; ++j) t[j] = Wm[q * 33 + h * 16 + j];  // back to rows
  }

  // cost = sum(T*C); C = -lkr/20
  float pp = 0.f;
#pragma unroll
  for (int j = 0; j < 16; ++j) pp = fmaf(t[j], -0.05f * lkr[j], pp);
  pp += __shfl_xor(pp, 1); pp += __shfl_xor(pp, 2); pp += __shfl_xor(pp, 4);
  pp += __shfl_xor(pp, 8); pp += __shfl_xor(pp, 16); pp += __shfl_xor(pp, 32);
  if (lane == 0) {
    costO[p] = pp;
    simO[p] = 1.0f / (1.0f + __expf(pp));  // sigmoid(-cost)
  }
  // T out (coalesced float4 from row view)
#pragma unroll
  for (int jj = 0; jj < 4; ++jj) {
    float4 o;
    o.x = t[jj * 4 + 0]; o.y = t[jj * 4 + 1];
    o.z = t[jj * 4 + 2]; o.w = t[jj * 4 + 3];
    *reinterpret_cast<float4*>(TO + (size_t)p * 1024 + q * 32 + h * 16 + jj * 4) = o;
  }
}

extern "C" void kernel_launch(void* const* d_in, const int* in_sizes, int n_in,
                              void* d_out, int out_size, void* d_ws, size_t ws_size,
                              hipStream_t stream) {
  const float* slots_q = (const float*)d_in[0];
  const float* slots_r = (const float*)d_in[1];
  const float* W1 = (const float*)d_in[2];
  const float* b1 = (const float*)d_in[3];
  const float* W2 = (const float*)d_in[4];
  const float* b2 = (const float*)d_in[5];
  float* out = (float*)d_out;

  const int Bn = in_sizes[0] / 8192;  // 32*256 per batch element
  u16* ws = (u16*)d_ws;               // 256 KB W fragments

  prep_w<<<dim3(512), dim3(256), 0, stream>>>(W1, W2, ws);

  float* simO = out;
  float* TO = out + Bn;
  float* CO = TO + (size_t)Bn * 1024;
  float* costO = CO + (size_t)Bn * 1024;

  gemm_cdist<<<dim3(Bn), dim3(512), 0, stream>>>(slots_q, slots_r, b1, b2, ws, CO);
  sinkhorn_mesh<<<dim3((Bn + 3) / 4), dim3(256), 0, stream>>>(CO, simO, TO, costO, Bn);
}

// Round 3
// 275.711 us; speedup vs baseline: 3.8853x; 1.3872x over previous
//
#include <hip/hip_runtime.h>

// SinkhornOT, split-kernel version for MI355X (gfx950).
// Kernel A (gemm_cdist, 1 block = 1 batch elem, 512 thr, 64KB LDS, 4 barriers):
//   X=[q;r] (64x256) -> bf16 fragment-major LDS -> H=relu(X@W1+b1) (MFMA)
//   -> Q=H@W2+b2 written as bf16 A-fragments (overlays X)
//   -> C via MFMA: C^2 = nq + nr - 2 q.r  (waves 0-3 dot tiles, waves 4-7 norms)
// Kernel B (sinkhorn_mesh, 1 wave = 1 problem, no barriers, wave-sync LDS):
//   15 log-domain Sinkhorn iters + T + 3 mesh iters + cost/sim + T out.
// prep_w packs W1/W2 as bf16 MFMA B-fragments (k-map k_local = 8g+j, used
// consistently for A and B so the bijection cancels; HW-validated r1/r2).

typedef unsigned short u16;
typedef short short8 __attribute__((ext_vector_type(8)));
typedef float f32x4  __attribute__((ext_vector_type(4)));

#define MFMA(a, b, c) __builtin_amdgcn_mfma_f32_16x16x32_bf16((a), (b), (c), 0, 0, 0)

static __device__ __forceinline__ u16 f2bf(float f) {  // RNE float->bf16 (finite)
  unsigned u = __float_as_uint(f);
  return (u16)((u + 0x7FFFu + ((u >> 16) & 1u)) >> 16);
}
static __device__ __forceinline__ float bf2f(u16 h) {
  return __uint_as_float(((unsigned)h) << 16);
}

// ---------------- W fragment prep ----------------
// lane l = g*16 + (n&15) holds B[k = ki*32 + 8g + j][col = 16*ctg + (n&15)]
// ws u16 layout: mat*65536 + ((ki*16 + ctg)*64 + lane)*8 + j   (256 KB total)
__global__ __launch_bounds__(256) void prep_w(const float* __restrict__ W1,
                                              const float* __restrict__ W2,
                                              u16* __restrict__ ws) {
  int id = blockIdx.x * 256 + threadIdx.x;  // 0..131071
  int mat = id >> 16;
  int e = id & 65535;   // e = k*256 + n
  int k = e >> 8, n = e & 255;
  float wv = (mat ? W2 : W1)[e];
  int ki = k >> 5, kl = k & 31;
  int g = kl >> 3, j = kl & 7;
  int lane = g * 16 + (n & 15);
  int ctg = n >> 4;
  ws[mat * 65536 + ((((ki * 16 + ctg) * 64 + lane) << 3) | j)] = f2bf(wv);
}

// ---------------- kernel A ----------------
struct __align__(16) SMemA {
  union { u16 Xf[16384]; u16 Qf[16384]; } u;  // 32KB: X frags, then Q frags
  u16 Hf[16384];                              // 32KB: H frags
  float nrm[64];                              // row norms of Q (0-31 q, 32-63 r)
};

// 64x256 @ 256x256: A fragment-major [ki*4+rt][lane][8] (contiguous b128/lane),
// B fragments from global ws. Wave w owns output cols [32w, 32w+32).
static __device__ __forceinline__ void gemm_frag(const u16* __restrict__ Af,
                                                 const u16* __restrict__ wf,
                                                 int w, int lane, f32x4 acc[4][2]) {
#pragma unroll
  for (int rt = 0; rt < 4; ++rt) {
    acc[rt][0] = f32x4{0.f, 0.f, 0.f, 0.f};
    acc[rt][1] = f32x4{0.f, 0.f, 0.f, 0.f};
  }
#pragma unroll
  for (int ki = 0; ki < 8; ++ki) {
    const u16* bp = wf + (((ki * 16 + 2 * w) * 64 + lane) << 3);
    short8 b0 = *reinterpret_cast<const short8*>(bp);        // 16B/lane, coalesced
    short8 b1 = *reinterpret_cast<const short8*>(bp + 512);  // ct=1 record
    short8 a[4];
#pragma unroll
    for (int rt = 0; rt < 4; ++rt)
      a[rt] = *reinterpret_cast<const short8*>(Af + (((ki * 4 + rt) * 64 + lane) << 3));
#pragma unroll
    for (int rt = 0; rt < 4; ++rt) {
      acc[rt][0] = MFMA(a[rt], b0, acc[rt][0]);
      acc[rt][1] = MFMA(a[rt], b1, acc[rt][1]);
    }
  }
}

__global__ __launch_bounds__(512, 4) void gemm_cdist(
    const float* __restrict__ slots_q, const float* __restrict__ slots_r,
    const float* __restrict__ b1, const float* __restrict__ b2,
    const u16* __restrict__ ws, float* __restrict__ CO) {
  __shared__ SMemA sm;
  const int tid = threadIdx.x, b = blockIdx.x;
  const int w = tid >> 6, lane = tid & 63, g = lane >> 4, ln = lane & 15;

  // ---- stage X fragment-major: slot s = (ki*4+rt)*64 + g*16 + ln ----
  {
    const float* srcq = slots_q + (size_t)b * 8192;
    const float* srcr = slots_r + (size_t)b * 8192;
#pragma unroll
    for (int ii = 0; ii < 4; ++ii) {
      int s = tid + ii * 512;  // 0..2047
      int ki = s >> 8, rt = (s >> 6) & 3, sg = (s >> 4) & 3, sln = s & 15;
      int row = rt * 16 + sln;
      const float* src = (row < 32) ? (srcq + row * 256) : (srcr + (row - 32) * 256);
      int k0 = ki * 32 + sg * 8;
      float4 v0 = *reinterpret_cast<const float4*>(src + k0);
      float4 v1 = *reinterpret_cast<const float4*>(src + k0 + 4);
      short8 o;
      o[0] = (short)f2bf(v0.x); o[1] = (short)f2bf(v0.y);
      o[2] = (short)f2bf(v0.z); o[3] = (short)f2bf(v0.w);
      o[4] = (short)f2bf(v1.x); o[5] = (short)f2bf(v1.y);
      o[6] = (short)f2bf(v1.z); o[7] = (short)f2bf(v1.w);
      *reinterpret_cast<short8*>(&sm.u.Xf[s << 3]) = o;  // contiguous, conflict-free
    }
  }
  float bv1a = b1[32 * w + ln], bv1b = b1[32 * w + 16 + ln];
  float bv2a = b2[32 * w + ln], bv2b = b2[32 * w + 16 + ln];
  __syncthreads();

  f32x4 acc[4][2];
  // ---- GEMM1: H = relu(X@W1 + b1), write H as A-fragments ----
  gemm_frag(sm.u.Xf, ws, w, lane, acc);
#pragma unroll
  for (int ct = 0; ct < 2; ++ct) {
    float bv = ct ? bv1b : bv1a;
#pragma unroll
    for (int rt = 0; rt < 4; ++rt)
#pragma unroll
      for (int ri = 0; ri < 4; ++ri) {
        // D layout: row = rt*16 + 4g + ri, col = 32w + 16ct + ln (verified r1)
        int lane2 = (2 * ct + (ln >> 3)) * 16 + 4 * g + ri;
        sm.Hf[(((w * 4 + rt) * 64 + lane2) << 3) | (ln & 7)] =
            f2bf(fmaxf(acc[rt][ct][ri] + bv, 0.0f));
      }
  }
  __syncthreads();

  // ---- GEMM2: Q = H@W2 + b2, write Q as A-fragments (overlays X) ----
  gemm_frag(sm.Hf, ws + 65536, w, lane, acc);
#pragma unroll
  for (int ct = 0; ct < 2; ++ct) {
    float bv = ct ? bv2b : bv2a;
#pragma unroll
    for (int rt = 0; rt < 4; ++rt)
#pragma unroll
      for (int ri = 0; ri < 4; ++ri) {
        int lane2 = (2 * ct + (ln >> 3)) * 16 + 4 * g + ri;
        sm.u.Qf[(((w * 4 + rt) * 64 + lane2) << 3) | (ln & 7)] =
            f2bf(acc[rt][ct][ri] + bv);
      }
  }
  __syncthreads();

  // ---- C^2 = nq + nr - 2 q.r : waves 0-3 dot tiles (MFMA), waves 4-7 norms ----
  f32x4 dacc = f32x4{0.f, 0.f, 0.f, 0.f};
  if (w < 4) {
    const int mt = w >> 1, nt = w & 1;  // q row-tile, r row-tile
#pragma unroll
    for (int ki = 0; ki < 8; ++ki) {
      // A = q rows tile mt; B = r rows tile (2+nt) — A-frag of r IS B-frag of r^T
      short8 aq = *reinterpret_cast<const short8*>(
          &sm.u.Qf[(((ki * 4 + mt) * 64 + lane) << 3)]);
      short8 br = *reinterpret_cast<const short8*>(
          &sm.u.Qf[(((ki * 4 + 2 + nt) * 64 + lane) << 3)]);
      dacc = MFMA(aq, br, dacc);
    }
  } else {
    const int t = w - 4;  // row-tile t: rows 16t .. 16t+15
    float s = 0.f;
#pragma unroll
    for (int ki = 0; ki < 8; ++ki) {
      short8 v = *reinterpret_cast<const short8*>(
          &sm.u.Qf[(((ki * 4 + t) * 64 + lane) << 3)]);
#pragma unroll
      for (int i = 0; i < 8; ++i) {
        float f = bf2f((u16)v[i]);
        s = fmaf(f, f, s);
      }
    }
    s += __shfl_xor(s, 16);  // reduce over k-groups g (same row, different k slice)
    s += __shfl_xor(s, 32);
    if (lane < 16) sm.nrm[t * 16 + lane] = s;
  }
  __syncthreads();

  if (w < 4) {
    const int mt = w >> 1, nt = w & 1;
    float* Cp = CO + (size_t)b * 1024;
#pragma unroll
    for (int ri = 0; ri < 4; ++ri) {
      int k = mt * 16 + 4 * g + ri;   // D layout: row = 4g+ri, col = ln
      int m = nt * 16 + ln;
      float sq = sm.nrm[k] + sm.nrm[32 + m] - 2.0f * dacc[ri];
      Cp[k * 32 + m] = sqrtf(fmaxf(sq, 0.0f));
    }
  }
}

// ---------------- kernel B: 1 wave = 1 problem, no barriers ----------------
__global__ __launch_bounds__(256, 4) void sinkhorn_mesh(
    const float* __restrict__ CO, float* __restrict__ simO,
    float* __restrict__ TO, float* __restrict__ costO, int Bn) {
  __shared__ float Wl[4][32 * 33];
  __shared__ float ABl[4][64];
  const int wv = threadIdx.x >> 6, lane = threadIdx.x & 63;
  const int p = blockIdx.x * 4 + wv;
  if (p >= Bn) return;
  const int h = lane >> 5, q = lane & 31;  // q = row k (row ops) / col (col ops)
  float* Wm = Wl[wv];
  float* LA = ABl[wv];
  float* LB = ABl[wv] + 32;
  const float* Cp = CO + (size_t)p * 1024;

  // lane holds row q cols [16h,16h+16) in lkr, col q rows [16h,16h+16) in lkc
  float lkr[16], lkc[16];
#pragma unroll
  for (int jj = 0; jj < 4; ++jj) {
    float4 v = *reinterpret_cast<const float4*>(Cp + q * 32 + h * 16 + jj * 4);
    int base = q * 33 + h * 16 + jj * 4;
    Wm[base + 0] = v.x; Wm[base + 1] = v.y; Wm[base + 2] = v.z; Wm[base + 3] = v.w;
    lkr[jj * 4 + 0] = -20.f * v.x; lkr[jj * 4 + 1] = -20.f * v.y;
    lkr[jj * 4 + 2] = -20.f * v.z; lkr[jj * 4 + 3] = -20.f * v.w;
  }
  LB[q] = 0.0f;
  __builtin_amdgcn_wave_barrier();
#pragma unroll
  for (int j = 0; j < 16; ++j) lkc[j] = -20.f * Wm[(h * 16 + j) * 33 + q];

  for (int it = 0; it < 15; ++it) {
    float v[16], mx, s;
#pragma unroll
    for (int j = 0; j < 16; ++j) v[j] = lkr[j] + LB[h * 16 + j];
    mx = v[0];
#pragma unroll
    for (int j = 1; j < 16; ++j) mx = fmaxf(mx, v[j]);
    mx = fmaxf(mx, __shfl_xor(mx, 32));
    s = 0.f;
#pragma unroll
    for (int j = 0; j < 16; ++j) s += __expf(v[j] - mx);
    s += __shfl_xor(s, 32);
    LA[q] = -(mx + __logf(s));  // both halves write identical value
    __builtin_amdgcn_wave_barrier();
#pragma unroll
    for (int j = 0; j < 16; ++j) v[j] = lkc[j] + LA[h * 16 + j];
    mx = v[0];
#pragma unroll
    for (int j = 1; j < 16; ++j) mx = fmaxf(mx, v[j]);
    mx = fmaxf(mx, __shfl_xor(mx, 32));
    s = 0.f;
#pragma unroll
    for (int j = 0; j < 16; ++j) s += __expf(v[j] - mx);
    s += __shfl_xor(s, 32);
    LB[q] = -(mx + __logf(s));
    __builtin_amdgcn_wave_barrier();
  }

  // T = exp(log_K + la + lb), row view
  float t[16];
  {
    float la = LA[q];
#pragma unroll
    for (int j = 0; j < 16; ++j) t[j] = __expf(lkr[j] + la + LB[h * 16 + j]);
  }

  // mesh: T=T^2; row-norm; col-norm (via LDS transpose; wave-sync only)
  for (int mi = 0; mi < 3; ++mi) {
    float s = 0.f;
#pragma unroll
    for (int j = 0; j < 16; ++j) { t[j] *= t[j]; s += t[j]; }
    s += __shfl_xor(s, 32);
    float inv = 1.0f / (s + 1e-8f);
#pragma unroll
    for (int j = 0; j < 16; ++j) Wm[q * 33 + h * 16 + j] = t[j] * inv;
    __builtin_amdgcn_wave_barrier();
#pragma unroll
    for (int j = 0; j < 16; ++j) t[j] = Wm[(h * 16 + j) * 33 + q];  // col view
    s = 0.f;
#pragma unroll
    for (int j = 0; j < 16; ++j) s += t[j];
    s += __shfl_xor(s, 32);
    inv = 1.0f / (s + 1e-8f);
#pragma unroll
    for (int j = 0; j < 16; ++j) Wm[(h * 16 + j) * 33 + q] = t[j] * inv;
    __builtin_amdgcn_wave_barrier();
#pragma unroll
    for (int j = 0; j < 16; ++j) t[j] = Wm[q * 33 + h * 16 + j];  // back to rows
  }

  // cost = sum(T*C); C = -lkr/20
  float pp = 0.f;
#pragma unroll
  for (int j = 0; j < 16; ++j) pp = fmaf(t[j], -0.05f * lkr[j], pp);
  pp += __shfl_xor(pp, 1); pp += __shfl_xor(pp, 2); pp += __shfl_xor(pp, 4);
  pp += __shfl_xor(pp, 8); pp += __shfl_xor(pp, 16); pp += __shfl_xor(pp, 32);
  if (lane == 0) {
    costO[p] = pp;
    simO[p] = 1.0f / (1.0f + __expf(pp));  // sigmoid(-cost)
  }
  // T out (coalesced float4 from row view)
#pragma unroll
  for (int jj = 0; jj < 4; ++jj) {
    float4 o;
    o.x = t[jj * 4 + 0]; o.y = t[jj * 4 + 1];
    o.z = t[jj * 4 + 2]; o.w = t[jj * 4 + 3];
    *reinterpret_cast<float4*>(TO + (size_t)p * 1024 + q * 32 + h * 16 + jj * 4) = o;
  }
}

extern "C" void kernel_launch(void* const* d_in, const int* in_sizes, int n_in,
                              void* d_out, int out_size, void* d_ws, size_t ws_size,
                              hipStream_t stream) {
  const float* slots_q = (const float*)d_in[0];
  const float* slots_r = (const float*)d_in[1];
  const float* W1 = (const float*)d_in[2];
  const float* b1 = (const float*)d_in[3];
  const float* W2 = (const float*)d_in[4];
  const float* b2 = (const float*)d_in[5];
  float* out = (float*)d_out;

  const int Bn = in_sizes[0] / 8192;  // 32*256 per batch element
  u16* ws = (u16*)d_ws;               // 256 KB W fragments

  prep_w<<<dim3(512), dim3(256), 0, stream>>>(W1, W2, ws);

  float* simO = out;
  float* TO = out + Bn;
  float* CO = TO + (size_t)Bn * 1024;
  float* costO = CO + (size_t)Bn * 1024;

  gemm_cdist<<<dim3(Bn), dim3(512), 0, stream>>>(slots_q, slots_r, b1, b2, ws, CO);
  sinkhorn_mesh<<<dim3((Bn + 3) / 4), dim3(256), 0, stream>>>(CO, simO, TO, costO, Bn);
}

// Round 4
// 261.650 us; speedup vs baseline: 4.0941x; 1.0537x over previous
//
#include <hip/hip_runtime.h>

// SinkhornOT, split-kernel version for MI355X (gfx950).
// Kernel A (gemm_cdist, 1 block = 1 batch elem, 512 thr, 33KB LDS, 6 barriers,
//           4 blocks/CU co-resident):
//   X=[q;r] (64x256) -> bf16 fragment-major LDS (single in-place buffer)
//   -> H=relu(X@W1+b1) (MFMA, in-place) -> Q=H@W2+b2 (in-place)
//   -> C via MFMA: C^2 = nq + nr - 2 q.r  (waves 0-3 dot tiles, waves 4-7 norms)
// Kernel B (sinkhorn_mesh, 1 wave = 1 problem, no barriers, wave-sync LDS):
//   15 log-domain Sinkhorn iters + T + 3 mesh iters + cost/sim + T out.
// prep_w packs W1/W2 as bf16 MFMA B-fragments (k-map k_local = 8g+j, used
// consistently for A and B so the bijection cancels; HW-validated r1-r3).

typedef unsigned short u16;
typedef short short8 __attribute__((ext_vector_type(8)));
typedef float f32x4  __attribute__((ext_vector_type(4)));

#define MFMA(a, b, c) __builtin_amdgcn_mfma_f32_16x16x32_bf16((a), (b), (c), 0, 0, 0)

static __device__ __forceinline__ u16 f2bf(float f) {  // RNE float->bf16 (finite)
  unsigned u = __float_as_uint(f);
  return (u16)((u + 0x7FFFu + ((u >> 16) & 1u)) >> 16);
}
static __device__ __forceinline__ float bf2f(u16 h) {
  return __uint_as_float(((unsigned)h) << 16);
}

// ---------------- W fragment prep ----------------
// lane l = g*16 + (n&15) holds B[k = ki*32 + 8g + j][col = 16*ctg + (n&15)]
// ws u16 layout: mat*65536 + ((ki*16 + ctg)*64 + lane)*8 + j   (256 KB total)
__global__ __launch_bounds__(256) void prep_w(const float* __restrict__ W1,
                                              const float* __restrict__ W2,
                                              u16* __restrict__ ws) {
  int id = blockIdx.x * 256 + threadIdx.x;  // 0..131071
  int mat = id >> 16;
  int e = id & 65535;   // e = k*256 + n
  int k = e >> 8, n = e & 255;
  float wv = (mat ? W2 : W1)[e];
  int ki = k >> 5, kl = k & 31;
  int g = kl >> 3, j = kl & 7;
  int lane = g * 16 + (n & 15);
  int ctg = n >> 4;
  ws[mat * 65536 + ((((ki * 16 + ctg) * 64 + lane) << 3) | j)] = f2bf(wv);
}

// ---------------- kernel A ----------------
struct __align__(16) SMemA {
  u16 F[16384];    // 32KB single buffer: X frags -> H frags -> Q frags (in place)
  float nrm[64];   // row norms of Q (0-31 q, 32-63 r)
};

// 64x256 @ 256x256: A fragment-major [ki*4+rt][lane][8] (contiguous b128/lane),
// B fragments from global ws. Wave w owns output cols [32w, 32w+32).
static __device__ __forceinline__ void gemm_frag(const u16* __restrict__ Af,
                                                 const u16* __restrict__ wf,
                                                 int w, int lane, f32x4 acc[4][2]) {
#pragma unroll
  for (int rt = 0; rt < 4; ++rt) {
    acc[rt][0] = f32x4{0.f, 0.f, 0.f, 0.f};
    acc[rt][1] = f32x4{0.f, 0.f, 0.f, 0.f};
  }
#pragma unroll
  for (int ki = 0; ki < 8; ++ki) {
    const u16* bp = wf + (((ki * 16 + 2 * w) * 64 + lane) << 3);
    short8 b0 = *reinterpret_cast<const short8*>(bp);        // 16B/lane, coalesced
    short8 b1 = *reinterpret_cast<const short8*>(bp + 512);  // ct=1 record
    short8 a[4];
#pragma unroll
    for (int rt = 0; rt < 4; ++rt)
      a[rt] = *reinterpret_cast<const short8*>(Af + (((ki * 4 + rt) * 64 + lane) << 3));
#pragma unroll
    for (int rt = 0; rt < 4; ++rt) {
      acc[rt][0] = MFMA(a[rt], b0, acc[rt][0]);
      acc[rt][1] = MFMA(a[rt], b1, acc[rt][1]);
    }
  }
}

__global__ __launch_bounds__(512, 8) void gemm_cdist(
    const float* __restrict__ slots_q, const float* __restrict__ slots_r,
    const float* __restrict__ b1, const float* __restrict__ b2,
    const u16* __restrict__ ws, float* __restrict__ CO) {
  __shared__ SMemA sm;
  const int tid = threadIdx.x, b = blockIdx.x;
  const int w = tid >> 6, lane = tid & 63, g = lane >> 4, ln = lane & 15;

  // ---- stage X fragment-major: slot s = (ki*4+rt)*64 + g*16 + ln ----
  {
    const float* srcq = slots_q + (size_t)b * 8192;
    const float* srcr = slots_r + (size_t)b * 8192;
#pragma unroll
    for (int ii = 0; ii < 4; ++ii) {
      int s = tid + ii * 512;  // 0..2047
      int ki = s >> 8, rt = (s >> 6) & 3, sg = (s >> 4) & 3, sln = s & 15;
      int row = rt * 16 + sln;
      const float* src = (row < 32) ? (srcq + row * 256) : (srcr + (row - 32) * 256);
      int k0 = ki * 32 + sg * 8;
      float4 v0 = *reinterpret_cast<const float4*>(src + k0);
      float4 v1 = *reinterpret_cast<const float4*>(src + k0 + 4);
      short8 o;
      o[0] = (short)f2bf(v0.x); o[1] = (short)f2bf(v0.y);
      o[2] = (short)f2bf(v0.z); o[3] = (short)f2bf(v0.w);
      o[4] = (short)f2bf(v1.x); o[5] = (short)f2bf(v1.y);
      o[6] = (short)f2bf(v1.z); o[7] = (short)f2bf(v1.w);
      *reinterpret_cast<short8*>(&sm.F[s << 3]) = o;  // contiguous, conflict-free
    }
  }
  float bv1a = b1[32 * w + ln], bv1b = b1[32 * w + 16 + ln];
  float bv2a = b2[32 * w + ln], bv2b = b2[32 * w + 16 + ln];
  __syncthreads();

  f32x4 acc[4][2];
  // ---- GEMM1: H = relu(X@W1 + b1) ----
  gemm_frag(sm.F, ws, w, lane, acc);
  __syncthreads();  // all X reads complete before overwriting F with H
#pragma unroll
  for (int ct = 0; ct < 2; ++ct) {
    float bv = ct ? bv1b : bv1a;
#pragma unroll
    for (int rt = 0; rt < 4; ++rt)
#pragma unroll
      for (int ri = 0; ri < 4; ++ri) {
        // D layout: row = rt*16 + 4g + ri, col = 32w + 16ct + ln (verified r1)
        int lane2 = (2 * ct + (ln >> 3)) * 16 + 4 * g + ri;
        sm.F[(((w * 4 + rt) * 64 + lane2) << 3) | (ln & 7)] =
            f2bf(fmaxf(acc[rt][ct][ri] + bv, 0.0f));
      }
  }
  __syncthreads();

  // ---- GEMM2: Q = H@W2 + b2 ----
  gemm_frag(sm.F, ws + 65536, w, lane, acc);
  __syncthreads();  // all H reads complete before overwriting F with Q
#pragma unroll
  for (int ct = 0; ct < 2; ++ct) {
    float bv = ct ? bv2b : bv2a;
#pragma unroll
    for (int rt = 0; rt < 4; ++rt)
#pragma unroll
      for (int ri = 0; ri < 4; ++ri) {
        int lane2 = (2 * ct + (ln >> 3)) * 16 + 4 * g + ri;
        sm.F[(((w * 4 + rt) * 64 + lane2) << 3) | (ln & 7)] =
            f2bf(acc[rt][ct][ri] + bv);
      }
  }
  __syncthreads();

  // ---- C^2 = nq + nr - 2 q.r : waves 0-3 dot tiles (MFMA), waves 4-7 norms ----
  f32x4 dacc = f32x4{0.f, 0.f, 0.f, 0.f};
  if (w < 4) {
    const int mt = w >> 1, nt = w & 1;  // q row-tile, r row-tile
#pragma unroll
    for (int ki = 0; ki < 8; ++ki) {
      // A = q rows tile mt; B = r rows tile (2+nt) — A-frag of r IS B-frag of r^T
      short8 aq = *reinterpret_cast<const short8*>(
          &sm.F[(((ki * 4 + mt) * 64 + lane) << 3)]);
      short8 br = *reinterpret_cast<const short8*>(
          &sm.F[(((ki * 4 + 2 + nt) * 64 + lane) << 3)]);
      dacc = MFMA(aq, br, dacc);
    }
  } else {
    const int t = w - 4;  // row-tile t: rows 16t .. 16t+15
    float s = 0.f;
#pragma unroll
    for (int ki = 0; ki < 8; ++ki) {
      short8 v = *reinterpret_cast<const short8*>(
          &sm.F[(((ki * 4 + t) * 64 + lane) << 3)]);
#pragma unroll
      for (int i = 0; i < 8; ++i) {
        float f = bf2f((u16)v[i]);
        s = fmaf(f, f, s);
      }
    }
    s += __shfl_xor(s, 16);  // reduce over k-groups g (same row, different k slice)
    s += __shfl_xor(s, 32);
    if (lane < 16) sm.nrm[t * 16 + lane] = s;
  }
  __syncthreads();

  if (w < 4) {
    const int mt = w >> 1, nt = w & 1;
    float* Cp = CO + (size_t)b * 1024;
#pragma unroll
    for (int ri = 0; ri < 4; ++ri) {
      int k = mt * 16 + 4 * g + ri;   // D layout: row = 4g+ri, col = ln
      int m = nt * 16 + ln;
      float sq = sm.nrm[k] + sm.nrm[32 + m] - 2.0f * dacc[ri];
      Cp[k * 32 + m] = sqrtf(fmaxf(sq, 0.0f));
    }
  }
}

// ---------------- kernel B: 1 wave = 1 problem, no barriers ----------------
__global__ __launch_bounds__(256, 4) void sinkhorn_mesh(
    const float* __restrict__ CO, float* __restrict__ simO,
    float* __restrict__ TO, float* __restrict__ costO, int Bn) {
  __shared__ float Wl[4][32 * 33];
  __shared__ float ABl[4][64];
  const int wv = threadIdx.x >> 6, lane = threadIdx.x & 63;
  const int p = blockIdx.x * 4 + wv;
  if (p >= Bn) return;
  const int h = lane >> 5, q = lane & 31;  // q = row k (row ops) / col (col ops)
  float* Wm = Wl[wv];
  float* LA = ABl[wv];
  float* LB = ABl[wv] + 32;
  const float* Cp = CO + (size_t)p * 1024;

  // lane holds row q cols [16h,16h+16) in lkr, col q rows [16h,16h+16) in lkc
  float lkr[16], lkc[16];
#pragma unroll
  for (int jj = 0; jj < 4; ++jj) {
    float4 v = *reinterpret_cast<const float4*>(Cp + q * 32 + h * 16 + jj * 4);
    int base = q * 33 + h * 16 + jj * 4;
    Wm[base + 0] = v.x; Wm[base + 1] = v.y; Wm[base + 2] = v.z; Wm[base + 3] = v.w;
    lkr[jj * 4 + 0] = -20.f * v.x; lkr[jj * 4 + 1] = -20.f * v.y;
    lkr[jj * 4 + 2] = -20.f * v.z; lkr[jj * 4 + 3] = -20.f * v.w;
  }
  LB[q] = 0.0f;
  __builtin_amdgcn_wave_barrier();
#pragma unroll
  for (int j = 0; j < 16; ++j) lkc[j] = -20.f * Wm[(h * 16 + j) * 33 + q];

  for (int it = 0; it < 15; ++it) {
    float v[16], mx, s;
#pragma unroll
    for (int j = 0; j < 16; ++j) v[j] = lkr[j] + LB[h * 16 + j];
    mx = v[0];
#pragma unroll
    for (int j = 1; j < 16; ++j) mx = fmaxf(mx, v[j]);
    mx = fmaxf(mx, __shfl_xor(mx, 32));
    s = 0.f;
#pragma unroll
    for (int j = 0; j < 16; ++j) s += __expf(v[j] - mx);
    s += __shfl_xor(s, 32);
    LA[q] = -(mx + __logf(s));  // both halves write identical value
    __builtin_amdgcn_wave_barrier();
#pragma unroll
    for (int j = 0; j < 16; ++j) v[j] = lkc[j] + LA[h * 16 + j];
    mx = v[0];
#pragma unroll
    for (int j = 1; j < 16; ++j) mx = fmaxf(mx, v[j]);
    mx = fmaxf(mx, __shfl_xor(mx, 32));
    s = 0.f;
#pragma unroll
    for (int j = 0; j < 16; ++j) s += __expf(v[j] - mx);
    s += __shfl_xor(s, 32);
    LB[q] = -(mx + __logf(s));
    __builtin_amdgcn_wave_barrier();
  }

  // T = exp(log_K + la + lb), row view
  float t[16];
  {
    float la = LA[q];
#pragma unroll
    for (int j = 0; j < 16; ++j) t[j] = __expf(lkr[j] + la + LB[h * 16 + j]);
  }

  // mesh: T=T^2; row-norm; col-norm (via LDS transpose; wave-sync only)
  for (int mi = 0; mi < 3; ++mi) {
    float s = 0.f;
#pragma unroll
    for (int j = 0; j < 16; ++j) { t[j] *= t[j]; s += t[j]; }
    s += __shfl_xor(s, 32);
    float inv = 1.0f / (s + 1e-8f);
#pragma unroll
    for (int j = 0; j < 16; ++j) Wm[q * 33 + h * 16 + j] = t[j] * inv;
    __builtin_amdgcn_wave_barrier();
#pragma unroll
    for (int j = 0; j < 16; ++j) t[j] = Wm[(h * 16 + j) * 33 + q];  // col view
    s = 0.f;
#pragma unroll
    for (int j = 0; j < 16; ++j) s += t[j];
    s += __shfl_xor(s, 32);
    inv = 1.0f / (s + 1e-8f);
#pragma unroll
    for (int j = 0; j < 16; ++j) Wm[(h * 16 + j) * 33 + q] = t[j] * inv;
    __builtin_amdgcn_wave_barrier();
#pragma unroll
    for (int j = 0; j < 16; ++j) t[j] = Wm[q * 33 + h * 16 + j];  // back to rows
  }

  // cost = sum(T*C); C = -lkr/20
  float pp = 0.f;
#pragma unroll
  for (int j = 0; j < 16; ++j) pp = fmaf(t[j], -0.05f * lkr[j], pp);
  pp += __shfl_xor(pp, 1); pp += __shfl_xor(pp, 2); pp += __shfl_xor(pp, 4);
  pp += __shfl_xor(pp, 8); pp += __shfl_xor(pp, 16); pp += __shfl_xor(pp, 32);
  if (lane == 0) {
    costO[p] = pp;
    simO[p] = 1.0f / (1.0f + __expf(pp));  // sigmoid(-cost)
  }
  // T out (coalesced float4 from row view)
#pragma unroll
  for (int jj = 0; jj < 4; ++jj) {
    float4 o;
    o.x = t[jj * 4 + 0]; o.y = t[jj * 4 + 1];
    o.z = t[jj * 4 + 2]; o.w = t[jj * 4 + 3];
    *reinterpret_cast<float4*>(TO + (size_t)p * 1024 + q * 32 + h * 16 + jj * 4) = o;
  }
}

extern "C" void kernel_launch(void* const* d_in, const int* in_sizes, int n_in,
                              void* d_out, int out_size, void* d_ws, size_t ws_size,
                              hipStream_t stream) {
  const float* slots_q = (const float*)d_in[0];
  const float* slots_r = (const float*)d_in[1];
  const float* W1 = (const float*)d_in[2];
  const float* b1 = (const float*)d_in[3];
  const float* W2 = (const float*)d_in[4];
  const float* b2 = (const float*)d_in[5];
  float* out = (float*)d_out;

  const int Bn = in_sizes[0] / 8192;  // 32*256 per batch element
  u16* ws = (u16*)d_ws;               // 256 KB W fragments

  prep_w<<<dim3(512), dim3(256), 0, stream>>>(W1, W2, ws);

  float* simO = out;
  float* TO = out + Bn;
  float* CO = TO + (size_t)Bn * 1024;
  float* costO = CO + (size_t)Bn * 1024;

  gemm_cdist<<<dim3(Bn), dim3(512), 0, stream>>>(slots_q, slots_r, b1, b2, ws, CO);
  sinkhorn_mesh<<<dim3((Bn + 3) / 4), dim3(256), 0, stream>>>(CO, simO, TO, costO, Bn);
}